// Round 4
// baseline (523.623 us; speedup 1.0000x reference)
//
#include <hip/hip_runtime.h>

typedef unsigned short u16;
typedef unsigned int   u32;

typedef short s16x8 __attribute__((ext_vector_type(8)));
typedef float f32x4 __attribute__((ext_vector_type(4)));

__device__ __forceinline__ float b2f(u16 u) {
    u32 x = ((u32)u) << 16;
    float f;
    __builtin_memcpy(&f, &x, 4);
    return f;
}

__device__ __forceinline__ u16 f2b(float f) {
    u32 x;
    __builtin_memcpy(&x, &f, 4);
    u32 r = (x + 0x7fffu + ((x >> 16) & 1u)) >> 16;
    return (u16)r;
}

__device__ __forceinline__ void gload_lds16(const u16* g, u16* l) {
    __builtin_amdgcn_global_load_lds(
        (const __attribute__((address_space(1))) void*)g,
        (__attribute__((address_space(3))) void*)l, 16, 0, 0);
}

// ---------------------------------------------------------------------------
// prep_convert: block 0 does point prep (bilinear corners + counting sort);
// blocks 1..1024 do fp32->bf16 param canonicalization. One dispatch.
// ---------------------------------------------------------------------------
__global__ void prep_convert(const float* __restrict__ kp,
                             int4* __restrict__ pts_off,
                             float4* __restrict__ pts_w,
                             int* __restrict__ perm,
                             const float* clw, const float* ihw, const float* cfw,
                             const float* clb, const float* ihb,
                             const float* lnw, const float* lnb, const float* cfb,
                             u16* __restrict__ canon) {
    if (blockIdx.x != 0) {
        const int total = 2632704;
        const int stride = (gridDim.x - 1) * 256;
        for (int i = (blockIdx.x - 1) * 256 + threadIdx.x; i < total; i += stride) {
            const float* src; int off;
            if (i < 262144)       { src = clw; off = i; }
            else if (i < 2359296) { src = ihw; off = i - 262144; }
            else if (i < 2621440) { src = cfw; off = i - 2359296; }
            else if (i < 2621952) { src = clb; off = i - 2621440; }
            else if (i < 2624000) { src = ihb; off = i - 2621952; }
            else if (i < 2628096) { src = lnw; off = i - 2624000; }
            else if (i < 2632192) { src = lnb; off = i - 2628096; }
            else                  { src = cfb; off = i - 2632192; }
            canon[i] = f2b(src[off]);
        }
        return;
    }
    __shared__ int cnt[256];
    __shared__ int base[256];
    const int t = threadIdx.x;
    cnt[t] = 0;
    __syncthreads();
    int buck[16];
    #pragma unroll
    for (int j = 0; j < 16; j++) {
        const int n = j * 256 + t;
        const float x = kp[n * 4 + 1] * 256.0f;
        const float y = kp[n * 4 + 2] * 256.0f;
        const int x0 = min(max((int)floorf(x), 0), 255);
        const int y0 = min(max((int)floorf(y), 0), 255);
        const int b = (y0 >> 3) * 8 + (x0 >> 5);
        buck[j] = b;
        atomicAdd(&cnt[b], 1);
    }
    __syncthreads();
    if (t < 64) {
        int a0 = cnt[t * 4], a1 = cnt[t * 4 + 1], a2 = cnt[t * 4 + 2], a3 = cnt[t * 4 + 3];
        int tot = a0 + a1 + a2 + a3;
        int pre = tot;
        #pragma unroll
        for (int off = 1; off < 64; off <<= 1) {
            int v = __shfl_up(pre, off);
            if (t >= off) pre += v;
        }
        int excl = pre - tot;
        base[t * 4]     = excl;
        base[t * 4 + 1] = excl + a0;
        base[t * 4 + 2] = excl + a0 + a1;
        base[t * 4 + 3] = excl + a0 + a1 + a2;
    }
    __syncthreads();
    cnt[t] = 0;
    __syncthreads();
    #pragma unroll
    for (int j = 0; j < 16; j++) {
        const int n = j * 256 + t;
        const float x = kp[n * 4 + 1] * 256.0f;
        const float y = kp[n * 4 + 2] * 256.0f;
        const float xf = floorf(x), yf = floorf(y);
        const int x0 = min(max((int)xf, 0), 255);
        const int x1 = min(max((int)xf + 1, 0), 255);
        const int y0 = min(max((int)yf, 0), 255);
        const int y1 = min(max((int)yf + 1, 0), 255);
        const float x0f = (float)x0, x1f = (float)x1;
        const float y0f = (float)y0, y1f = (float)y1;
        float4 w;
        w.x = (x1f - x) * (y1f - y);
        w.y = (x1f - x) * (y - y0f);
        w.z = (x - x0f) * (y1f - y);
        w.w = (x - x0f) * (y - y0f);
        int4 o;
        o.x = y0 * 256 + x0;
        o.y = y1 * 256 + x0;
        o.z = y0 * 256 + x1;
        o.w = y1 * 256 + x1;
        const int b = buck[j];
        const int pos = base[b] + atomicAdd(&cnt[b], 1);
        perm[pos] = n;
        pts_off[pos] = o;
        pts_w[pos] = w;
    }
}

// ---------------------------------------------------------------------------
// interp_sorted: grid dim3(1024, 4) — channel x point-quarter.
// ---------------------------------------------------------------------------
__global__ __launch_bounds__(256) void interp_sorted(const float* __restrict__ bev,
                                                     const int4* __restrict__ pts_off,
                                                     const float4* __restrict__ pts_w,
                                                     u16* __restrict__ img) {
    const int c = blockIdx.x;
    const float* plane = bev + (size_t)c * 65536;
    const int base_i = blockIdx.y * 1024;
    const int t = threadIdx.x;
    #pragma unroll
    for (int j = 0; j < 4; j++) {
        const int i = base_i + j * 256 + t;
        const int4 o = pts_off[i];
        const float4 w = pts_w[i];
        const float v = plane[o.x] * w.x + plane[o.y] * w.y +
                        plane[o.z] * w.z + plane[o.w] * w.w;
        img[(size_t)c * 4096 + i] = f2b(v);
    }
}

// ---------------------------------------------------------------------------
// transpose_both: grid (64, 24). y<16: img (u16, R=1024, perm); y>=16: pf
// (f32, R=512).
// ---------------------------------------------------------------------------
__global__ void transpose_both(const u16* __restrict__ img, const float* __restrict__ pf,
                               u16* __restrict__ imgT, u16* __restrict__ pfT,
                               const int* __restrict__ perm) {
    __shared__ u16 tile[64][65];
    const int t = threadIdx.x;
    int by = blockIdx.y;
    int isf, R;
    const int* prm;
    u16* out;
    if (by < 16) { isf = 0; R = 1024; prm = perm; out = imgT; }
    else         { isf = 1; R = 512;  prm = nullptr; out = pfT; by -= 16; }
    const int r0 = by * 64, c0 = blockIdx.x * 64;
    #pragma unroll
    for (int i = 0; i < 16; i++) {
        int idx = i * 256 + t;
        int r = idx >> 6, c = idx & 63;
        tile[r][c] = isf ? f2b(pf[(size_t)(r0 + r) * 4096 + c0 + c])
                         : img[(size_t)(r0 + r) * 4096 + c0 + c];
    }
    __syncthreads();
    #pragma unroll
    for (int i = 0; i < 16; i++) {
        int idx = i * 256 + t;
        int c = idx >> 6, r = idx & 63;
        int row = prm ? prm[c0 + c] : (c0 + c);
        out[(size_t)row * R + r0 + r] = tile[r][c];
    }
}

// ---------------------------------------------------------------------------
// gemm_k256: deep-pipelined MFMA GEMM for the big (keys) GEMM.
// BM=128, BN=256, BK=64, 512 threads (8 waves, 2Mx4N), 3-deep LDS ring
// (144 KB), counted vmcnt(6) once per K-tile placed BEFORE the end barrier,
// setprio around MFMA cluster, XOR-swizzle chunk^=row&7 (both-sides:
// pre-swizzled global source + swizzled ds_read, linear gload dest),
// XCD-bijective block swizzle. Invariant: at end of iter j (post vmcnt(6)),
// only tile j+2's 6 loads remain outstanding -> tile j+1 landed; barrier
// publishes to all waves. Slot reuse safe: tile j-1's ds_reads complete
// before its MFMA (lgkmcnt), which precedes the end-of-iter barrier, which
// precedes the slot-(j+2)%3 overwrite.
// ---------------------------------------------------------------------------
__global__ __launch_bounds__(512, 1) void gemm_k256(const u16* __restrict__ A,
                                                    const u16* __restrict__ BT,
                                                    const u16* __restrict__ bias,
                                                    u16* __restrict__ Cout,
                                                    int M, int N, int K) {
    __shared__ __align__(16) u16 As[3][128 * 64];   // 48 KB
    __shared__ __align__(16) u16 Bs[3][256 * 64];   // 96 KB
    const int tid = threadIdx.x;
    const int lane = tid & 63;
    const int w = tid >> 6;
    const int bid = blockIdx.x;
    const int swz = (bid & 7) * 32 + (bid >> 3);    // bijective, 256 % 8 == 0
    const int m0 = (swz >> 4) * 128;
    const int n0 = (swz & 15) * 256;
    const int wm = (w >> 2) * 64;
    const int wn = (w & 3) * 64;
    const int q = lane >> 4, r = lane & 15;

    // staging maps: rows of 64 bf16 = 128B = 8 chunks of 16B.
    // involution on chunks within a row: chunk ^= (row & 7).
    int ra[2], ca[2];
    #pragma unroll
    for (int i = 0; i < 2; i++) {
        int s = i * 512 + tid;
        ra[i] = s >> 3;
        ca[i] = ((s & 7) ^ (ra[i] & 7)) * 8;
    }
    int rb[4], cb[4];
    #pragma unroll
    for (int i = 0; i < 4; i++) {
        int s = i * 512 + tid;
        rb[i] = s >> 3;
        cb[i] = ((s & 7) ^ (rb[i] & 7)) * 8;
    }

    const int nkt = K >> 6;   // 16
    f32x4 acc[4][4] = {};

    // prologue: stage tiles 0 and 1
    #pragma unroll
    for (int tkt = 0; tkt < 2; tkt++) {
        const int kb = tkt * 64;
        #pragma unroll
        for (int i = 0; i < 2; i++)
            gload_lds16(&A[(size_t)(m0 + ra[i]) * K + kb + ca[i]], &As[tkt][(i * 512 + tid) * 8]);
        #pragma unroll
        for (int i = 0; i < 4; i++)
            gload_lds16(&BT[(size_t)(n0 + rb[i]) * K + kb + cb[i]], &Bs[tkt][(i * 512 + tid) * 8]);
    }
    asm volatile("s_waitcnt vmcnt(6)" ::: "memory");   // tile 0 landed
    __builtin_amdgcn_s_barrier();

    for (int kt = 0; kt < nkt; kt++) {
        const int sl = kt % 3;
        const u16* Ab = As[sl];
        const u16* Bb = Bs[sl];
        s16x8 af[4][2], bf[4][2];
        #pragma unroll
        for (int mt = 0; mt < 4; mt++) {
            const int row = wm + mt * 16 + r;
            #pragma unroll
            for (int kh = 0; kh < 2; kh++)
                af[mt][kh] = *(const s16x8*)&Ab[row * 64 + (((kh * 4 + q) ^ (r & 7)) * 8)];
        }
        #pragma unroll
        for (int nt = 0; nt < 4; nt++) {
            const int row = wn + nt * 16 + r;
            #pragma unroll
            for (int kh = 0; kh < 2; kh++)
                bf[nt][kh] = *(const s16x8*)&Bb[row * 64 + (((kh * 4 + q) ^ (r & 7)) * 8)];
        }
        if (kt + 2 < nkt) {
            const int s2 = (kt + 2) % 3;
            const int kb = (kt + 2) * 64;
            #pragma unroll
            for (int i = 0; i < 2; i++)
                gload_lds16(&A[(size_t)(m0 + ra[i]) * K + kb + ca[i]], &As[s2][(i * 512 + tid) * 8]);
            #pragma unroll
            for (int i = 0; i < 4; i++)
                gload_lds16(&BT[(size_t)(n0 + rb[i]) * K + kb + cb[i]], &Bs[s2][(i * 512 + tid) * 8]);
        }
        __builtin_amdgcn_s_barrier();
        __builtin_amdgcn_s_setprio(1);
        #pragma unroll
        for (int kh = 0; kh < 2; kh++)
            #pragma unroll
            for (int mt = 0; mt < 4; mt++)
                #pragma unroll
                for (int nt = 0; nt < 4; nt++)
                    acc[mt][nt] = __builtin_amdgcn_mfma_f32_16x16x32_bf16(
                        af[mt][kh], bf[nt][kh], acc[mt][nt], 0, 0, 0);
        __builtin_amdgcn_s_setprio(0);
        if (kt + 2 < nkt) asm volatile("s_waitcnt vmcnt(6)" ::: "memory");
        else              asm volatile("s_waitcnt vmcnt(0)" ::: "memory");
        __builtin_amdgcn_s_barrier();
    }

    const int cn = lane & 15;
    #pragma unroll
    for (int mt = 0; mt < 4; mt++) {
        #pragma unroll
        for (int i = 0; i < 4; i++) {
            const int gm = m0 + wm + mt * 16 + q * 4 + i;
            const float bv = b2f(bias[gm]);
            #pragma unroll
            for (int nt = 0; nt < 4; nt++) {
                const int gn = n0 + wn + nt * 16 + cn;
                Cout[(size_t)gm * N + gn] = f2b(acc[mt][nt][i] + bv);
            }
        }
    }
}

// ---------------------------------------------------------------------------
// MFMA GEMM (m97 structure) for the small GEMMs. BM=64, BN=128, BK=32,
// 256 threads, gload_lds linear LDS. OB=0: fp32 out.
// ---------------------------------------------------------------------------
template <int BM, int OB>
__global__ __launch_bounds__(256) void gemm_bt(const u16* __restrict__ A,
                                               const u16* __restrict__ BT,
                                               const u16* __restrict__ bias,
                                               void* __restrict__ Cout,
                                               int M, int N, int K) {
    constexpr int MT = BM / 32;
    __shared__ __align__(16) u16 As[BM * 32];
    __shared__ __align__(16) u16 Bs[128 * 32];
    const int tid = threadIdx.x;
    const int lane = tid & 63;
    const int w = tid >> 6;
    const int m0 = blockIdx.y * BM;
    const int n0 = blockIdx.x * 128;
    const int wm = (w >> 1) * (BM / 2);
    const int wn = (w & 1) * 64;

    f32x4 acc[MT][4] = {};

    const int q = lane >> 4, r = lane & 15;

    for (int k0 = 0; k0 < K; k0 += 32) {
        __syncthreads();
        #pragma unroll
        for (int i = 0; i < BM / 64; i++) {
            int s = i * 256 + tid;
            gload_lds16(&A[(size_t)(m0 + (s >> 2)) * K + k0 + (s & 3) * 8], &As[s * 8]);
        }
        #pragma unroll
        for (int i = 0; i < 2; i++) {
            int s = i * 256 + tid;
            gload_lds16(&BT[(size_t)(n0 + (s >> 2)) * K + k0 + (s & 3) * 8], &Bs[s * 8]);
        }
        __syncthreads();

        s16x8 af[MT], bfr[4];
        #pragma unroll
        for (int mt = 0; mt < MT; mt++)
            af[mt] = *(const s16x8*)&As[(wm + mt * 16 + r) * 32 + q * 8];
        #pragma unroll
        for (int nt = 0; nt < 4; nt++)
            bfr[nt] = *(const s16x8*)&Bs[(wn + nt * 16 + r) * 32 + q * 8];
        #pragma unroll
        for (int mt = 0; mt < MT; mt++)
            #pragma unroll
            for (int nt = 0; nt < 4; nt++)
                acc[mt][nt] = __builtin_amdgcn_mfma_f32_16x16x32_bf16(
                    af[mt], bfr[nt], acc[mt][nt], 0, 0, 0);
    }

    const int cn = lane & 15;
    #pragma unroll
    for (int mt = 0; mt < MT; mt++) {
        #pragma unroll
        for (int i = 0; i < 4; i++) {
            int gm = m0 + wm + mt * 16 + q * 4 + i;
            float bv = b2f(bias[gm]);
            #pragma unroll
            for (int nt = 0; nt < 4; nt++) {
                int gn = n0 + wn + nt * 16 + cn;
                float v = acc[mt][nt][i] + bv;
                if (OB)
                    ((u16*)Cout)[(size_t)gm * N + gn] = f2b(v);
                else
                    ((float*)Cout)[(size_t)gm * N + gn] = v;
            }
        }
    }
}

// ---------------------------------------------------------------------------
// score_t: fused score + softmax + t-computation + LN-stats.
// Grid 64 blocks x 512 threads; block owns 64 n-columns. Phase 1: per-head
// score partials -> LDS reduce -> softmax -> wm (LDS + global). Phase 2:
// re-stream the SAME keys/lq slice (L2-hot, ~384 KB/block) to compute
// t = lq + sum_h wm*keys, write fp32 tbuf, and write per-(block,l) partial
// sum/sumsq to stat_part (deterministic, no atomics, no pre-zeroing).
// ---------------------------------------------------------------------------
__global__ __launch_bounds__(512) void score_t(const u16* __restrict__ keys,
                                               const float* __restrict__ lq,
                                               float* __restrict__ wm_ws,
                                               float* __restrict__ out,
                                               float* __restrict__ tbuf,
                                               float* __restrict__ stat_part) {
    __shared__ float red[4][8][64];
    __shared__ float wm_sh[4][64];
    const int nl = threadIdx.x & 63;
    const int lg = threadIdx.x >> 6;          // wave index == l-group
    const int n = blockIdx.x * 64 + nl;
    float acc[4] = {0.f, 0.f, 0.f, 0.f};
    #pragma unroll 8
    for (int i = 0; i < 64; i++) {
        const int l = lg * 64 + i;
        const float qv = lq[l * 4096 + n];
        #pragma unroll
        for (int h = 0; h < 4; h++)
            acc[h] += b2f(keys[(size_t)(h * 512 + l) * 4096 + n]) * qv;
    }
    #pragma unroll
    for (int h = 0; h < 4; h++) red[h][lg][nl] = acc[h];
    __syncthreads();
    if (threadIdx.x < 64) {
        const float scale = 0.044194173824159216f;  // 1/sqrt(512)
        float s[4];
        #pragma unroll
        for (int h = 0; h < 4; h++) {
            float v = 0.f;
            #pragma unroll
            for (int c = 0; c < 8; c++) v += red[h][c][nl];
            s[h] = v * scale;
        }
        float mx = fmaxf(fmaxf(s[0], s[1]), fmaxf(s[2], s[3]));
        float e[4], sum = 0.f;
        #pragma unroll
        for (int h = 0; h < 4; h++) { e[h] = expf(s[h] - mx); sum += e[h]; }
        const float inv = 1.0f / sum;
        #pragma unroll
        for (int h = 0; h < 4; h++) {
            float wv = e[h] * inv;
            wm_sh[h][nl] = wv;
            wm_ws[h * 4096 + n] = wv;
            out[2097152 + (size_t)h * 4096 + n] = wv;
        }
    }
    __syncthreads();
    // phase 2: t + partial stats (keys/lq slice is L2-hot from phase 1)
    float wv[4];
    #pragma unroll
    for (int h = 0; h < 4; h++) wv[h] = wm_sh[h][nl];
    const int sbase = blockIdx.x * 1024;
    for (int j = 0; j < 64; j++) {
        const int l = lg * 64 + j;
        float v = lq[l * 4096 + n];
        #pragma unroll
        for (int h = 0; h < 4; h++)
            v += wv[h] * b2f(keys[(size_t)(h * 512 + l) * 4096 + n]);
        tbuf[(size_t)l * 4096 + n] = v;
        float s = v, ss = v * v;
        #pragma unroll
        for (int off = 32; off > 0; off >>= 1) {
            s += __shfl_down(s, off);
            ss += __shfl_down(ss, off);
        }
        if (nl == 0) {
            stat_part[sbase + l] = s;
            stat_part[sbase + 512 + l] = ss;
        }
    }
}

// ---------------------------------------------------------------------------
// tnorm_transpose: reduces stat partials (64 blocks), applies LayerNorm
// during the tile load of fp32 tbuf[l][n], writes bf16 tT[n][l].
// Grid dim3(64 n-tiles, 8 l-tiles).
// ---------------------------------------------------------------------------
__global__ __launch_bounds__(256) void tnorm_transpose(const float* __restrict__ tbuf,
                                                       const float* __restrict__ stat_part,
                                                       const float* __restrict__ lnw,
                                                       const float* __restrict__ lnb,
                                                       u16* __restrict__ tT) {
    __shared__ u16 tile[64][65];
    __shared__ float smu[64], srs[64], slw[64], slb[64];
    const int t = threadIdx.x;
    const int l0 = blockIdx.y * 64, n0 = blockIdx.x * 64;
    if (t < 64) {
        float s = 0.f, ss = 0.f;
        #pragma unroll 8
        for (int b = 0; b < 64; b++) {
            s  += stat_part[b * 1024 + l0 + t];
            ss += stat_part[b * 1024 + 512 + l0 + t];
        }
        const float mu = s * (1.0f / 4096.0f);
        smu[t] = mu;
        srs[t] = rsqrtf(ss * (1.0f / 4096.0f) - mu * mu + 1e-5f);
        slw[t] = lnw[n0 + t];
        slb[t] = lnb[n0 + t];
    }
    __syncthreads();
    #pragma unroll
    for (int i = 0; i < 16; i++) {
        int idx = i * 256 + t;
        int r = idx >> 6, c = idx & 63;
        const float v = (tbuf[(size_t)(l0 + r) * 4096 + n0 + c] - smu[r]) * srs[r] * slw[c] + slb[c];
        tile[r][c] = f2b(v);
    }
    __syncthreads();
    #pragma unroll
    for (int i = 0; i < 16; i++) {
        int idx = i * 256 + t;
        int c = idx >> 6, r = idx & 63;
        tT[(size_t)(n0 + c) * 512 + l0 + r] = tile[r][c];
    }
}

// ---------------------------------------------------------------------------
extern "C" void kernel_launch(void* const* d_in, const int* in_sizes, int n_in,
                              void* d_out, int out_size, void* d_ws, size_t ws_size,
                              hipStream_t stream) {
    const float* pf  = (const float*)d_in[0];
    const float* kp  = (const float*)d_in[1];
    const float* bev = (const float*)d_in[2];
    const float* clw = (const float*)d_in[3];
    const float* clb = (const float*)d_in[4];
    const float* ihw = (const float*)d_in[5];
    const float* ihb = (const float*)d_in[6];
    const float* lnw = (const float*)d_in[7];
    const float* lnb = (const float*)d_in[8];
    const float* cfw = (const float*)d_in[9];
    const float* cfb = (const float*)d_in[10];
    float* out = (float*)d_out;

    char* ws = (char*)d_ws;
    u16*    img     = (u16*)(ws + 0);                    // 8 MB (1024,4096) sorted
    float*  tbuf    = (float*)(ws + 0);                  // 8 MB fp32 t, reuse after T
    u16*    imgT    = (u16*)(ws + (8ull << 20));         // 8 MB (4096,1024)
    float*  lq      = (float*)(ws + (8ull << 20));       // 8 MB, reuse after gemm-keys
    u16*    keys    = (u16*)(ws + (16ull << 20));        // 16 MB (2048,4096)
    u16*    pfT     = (u16*)(ws + (32ull << 20));        // 4 MB (4096,512)
    u16*    tT      = (u16*)(ws + (32ull << 20));        // reuse after gemm-lq
    float*  wm_ws   = (float*)(ws + (36ull << 20));
    u16*    canon   = (u16*)  (ws + (36ull << 20) + 131072);
    int4*   pts_off = (int4*) (ws + (42ull << 20));           // 64 KB
    float4* pts_w   = (float4*)(ws + (42ull << 20) + 65536);  // 64 KB
    int*    perm    = (int*)  (ws + (42ull << 20) + 131072);  // 16 KB
    float*  stat_p  = (float*)(ws + (43ull << 20));           // 256 KB partials

    u16* clw_c = canon;
    u16* ihw_c = canon + 262144;
    u16* cfw_c = canon + 2359296;
    u16* clb_c = canon + 2621440;
    u16* ihb_c = canon + 2621952;
    u16* cfb_c = canon + 2632192;

    prep_convert<<<1025, 256, 0, stream>>>(kp, pts_off, pts_w, perm,
                                           clw, ihw, cfw, clb, ihb, lnw, lnb, cfb, canon);
    interp_sorted<<<dim3(1024, 4), 256, 0, stream>>>(bev, pts_off, pts_w, img);
    transpose_both<<<dim3(64, 24), 256, 0, stream>>>(img, pf, imgT, pfT, perm);
    gemm_k256<<<256, 512, 0, stream>>>(ihw_c, imgT, ihb_c, keys, 2048, 4096, 1024);
    gemm_bt<64, 0><<<dim3(32, 8), 256, 0, stream>>>(clw_c, pfT, clb_c, lq, 512, 4096, 512);
    score_t<<<64, 512, 0, stream>>>(keys, lq, wm_ws, out, tbuf, stat_p);
    tnorm_transpose<<<dim3(64, 8), 256, 0, stream>>>(tbuf, stat_p, lnw, lnb, tT);
    gemm_bt<64, 0><<<dim3(32, 8), 256, 0, stream>>>(cfw_c, tT, cfb_c, out, 512, 4096, 512);
}

// Round 5
// 486.805 us; speedup vs baseline: 1.0756x; 1.0756x over previous
//
#include <hip/hip_runtime.h>

typedef unsigned short u16;
typedef unsigned int   u32;

typedef short s16x8 __attribute__((ext_vector_type(8)));
typedef float f32x4 __attribute__((ext_vector_type(4)));

__device__ __forceinline__ float b2f(u16 u) {
    u32 x = ((u32)u) << 16;
    float f;
    __builtin_memcpy(&f, &x, 4);
    return f;
}

__device__ __forceinline__ u16 f2b(float f) {
    u32 x;
    __builtin_memcpy(&x, &f, 4);
    u32 r = (x + 0x7fffu + ((x >> 16) & 1u)) >> 16;
    return (u16)r;
}

__device__ __forceinline__ void gload_lds16(const u16* g, u16* l) {
    __builtin_amdgcn_global_load_lds(
        (const __attribute__((address_space(1))) void*)g,
        (__attribute__((address_space(3))) void*)l, 16, 0, 0);
}

// ---------------------------------------------------------------------------
// prep_convert: block 0 does point prep (bilinear corners + counting sort);
// blocks 1..1024 do fp32->bf16 param canonicalization. One dispatch.
// ---------------------------------------------------------------------------
__global__ void prep_convert(const float* __restrict__ kp,
                             int4* __restrict__ pts_off,
                             float4* __restrict__ pts_w,
                             int* __restrict__ perm,
                             const float* clw, const float* ihw, const float* cfw,
                             const float* clb, const float* ihb,
                             const float* lnw, const float* lnb, const float* cfb,
                             u16* __restrict__ canon) {
    if (blockIdx.x != 0) {
        const int total = 2632704;
        const int stride = (gridDim.x - 1) * 256;
        for (int i = (blockIdx.x - 1) * 256 + threadIdx.x; i < total; i += stride) {
            const float* src; int off;
            if (i < 262144)       { src = clw; off = i; }
            else if (i < 2359296) { src = ihw; off = i - 262144; }
            else if (i < 2621440) { src = cfw; off = i - 2359296; }
            else if (i < 2621952) { src = clb; off = i - 2621440; }
            else if (i < 2624000) { src = ihb; off = i - 2621952; }
            else if (i < 2628096) { src = lnw; off = i - 2624000; }
            else if (i < 2632192) { src = lnb; off = i - 2628096; }
            else                  { src = cfb; off = i - 2632192; }
            canon[i] = f2b(src[off]);
        }
        return;
    }
    __shared__ int cnt[256];
    __shared__ int base[256];
    const int t = threadIdx.x;
    cnt[t] = 0;
    __syncthreads();
    int buck[16];
    #pragma unroll
    for (int j = 0; j < 16; j++) {
        const int n = j * 256 + t;
        const float x = kp[n * 4 + 1] * 256.0f;
        const float y = kp[n * 4 + 2] * 256.0f;
        const int x0 = min(max((int)floorf(x), 0), 255);
        const int y0 = min(max((int)floorf(y), 0), 255);
        const int b = (y0 >> 3) * 8 + (x0 >> 5);
        buck[j] = b;
        atomicAdd(&cnt[b], 1);
    }
    __syncthreads();
    if (t < 64) {
        int a0 = cnt[t * 4], a1 = cnt[t * 4 + 1], a2 = cnt[t * 4 + 2], a3 = cnt[t * 4 + 3];
        int tot = a0 + a1 + a2 + a3;
        int pre = tot;
        #pragma unroll
        for (int off = 1; off < 64; off <<= 1) {
            int v = __shfl_up(pre, off);
            if (t >= off) pre += v;
        }
        int excl = pre - tot;
        base[t * 4]     = excl;
        base[t * 4 + 1] = excl + a0;
        base[t * 4 + 2] = excl + a0 + a1;
        base[t * 4 + 3] = excl + a0 + a1 + a2;
    }
    __syncthreads();
    cnt[t] = 0;
    __syncthreads();
    #pragma unroll
    for (int j = 0; j < 16; j++) {
        const int n = j * 256 + t;
        const float x = kp[n * 4 + 1] * 256.0f;
        const float y = kp[n * 4 + 2] * 256.0f;
        const float xf = floorf(x), yf = floorf(y);
        const int x0 = min(max((int)xf, 0), 255);
        const int x1 = min(max((int)xf + 1, 0), 255);
        const int y0 = min(max((int)yf, 0), 255);
        const int y1 = min(max((int)yf + 1, 0), 255);
        const float x0f = (float)x0, x1f = (float)x1;
        const float y0f = (float)y0, y1f = (float)y1;
        float4 w;
        w.x = (x1f - x) * (y1f - y);
        w.y = (x1f - x) * (y - y0f);
        w.z = (x - x0f) * (y1f - y);
        w.w = (x - x0f) * (y - y0f);
        int4 o;
        o.x = y0 * 256 + x0;
        o.y = y1 * 256 + x0;
        o.z = y0 * 256 + x1;
        o.w = y1 * 256 + x1;
        const int b = buck[j];
        const int pos = base[b] + atomicAdd(&cnt[b], 1);
        perm[pos] = n;
        pts_off[pos] = o;
        pts_w[pos] = w;
    }
}

// ---------------------------------------------------------------------------
// interp_sorted: grid dim3(1024, 4) — channel x point-quarter.
// ---------------------------------------------------------------------------
__global__ __launch_bounds__(256) void interp_sorted(const float* __restrict__ bev,
                                                     const int4* __restrict__ pts_off,
                                                     const float4* __restrict__ pts_w,
                                                     u16* __restrict__ img) {
    const int c = blockIdx.x;
    const float* plane = bev + (size_t)c * 65536;
    const int base_i = blockIdx.y * 1024;
    const int t = threadIdx.x;
    #pragma unroll
    for (int j = 0; j < 4; j++) {
        const int i = base_i + j * 256 + t;
        const int4 o = pts_off[i];
        const float4 w = pts_w[i];
        const float v = plane[o.x] * w.x + plane[o.y] * w.y +
                        plane[o.z] * w.z + plane[o.w] * w.w;
        img[(size_t)c * 4096 + i] = f2b(v);
    }
}

// ---------------------------------------------------------------------------
// transpose_both: grid (64, 24). y<16: img (u16, R=1024, perm); y>=16: pf
// (f32, R=512).
// ---------------------------------------------------------------------------
__global__ void transpose_both(const u16* __restrict__ img, const float* __restrict__ pf,
                               u16* __restrict__ imgT, u16* __restrict__ pfT,
                               const int* __restrict__ perm) {
    __shared__ u16 tile[64][65];
    const int t = threadIdx.x;
    int by = blockIdx.y;
    int isf, R;
    const int* prm;
    u16* out;
    if (by < 16) { isf = 0; R = 1024; prm = perm; out = imgT; }
    else         { isf = 1; R = 512;  prm = nullptr; out = pfT; by -= 16; }
    const int r0 = by * 64, c0 = blockIdx.x * 64;
    #pragma unroll
    for (int i = 0; i < 16; i++) {
        int idx = i * 256 + t;
        int r = idx >> 6, c = idx & 63;
        tile[r][c] = isf ? f2b(pf[(size_t)(r0 + r) * 4096 + c0 + c])
                         : img[(size_t)(r0 + r) * 4096 + c0 + c];
    }
    __syncthreads();
    #pragma unroll
    for (int i = 0; i < 16; i++) {
        int idx = i * 256 + t;
        int c = idx >> 6, r = idx & 63;
        int row = prm ? prm[c0 + c] : (c0 + c);
        out[(size_t)row * R + r0 + r] = tile[r][c];
    }
}

// ---------------------------------------------------------------------------
// Transpose: in[R][C] -> out[C][R] bf16 (u16 in). Used for tnorm -> tT.
// ---------------------------------------------------------------------------
__global__ void transpose_u16(const u16* __restrict__ in, u16* __restrict__ out,
                              int R, int C) {
    __shared__ u16 tile[64][65];
    const int t = threadIdx.x;
    const int r0 = blockIdx.y * 64, c0 = blockIdx.x * 64;
    #pragma unroll
    for (int i = 0; i < 16; i++) {
        int idx = i * 256 + t;
        int r = idx >> 6, c = idx & 63;
        tile[r][c] = in[(size_t)(r0 + r) * C + c0 + c];
    }
    __syncthreads();
    #pragma unroll
    for (int i = 0; i < 16; i++) {
        int idx = i * 256 + t;
        int c = idx >> 6, r = idx & 63;
        out[(size_t)(c0 + c) * R + r0 + r] = tile[r][c];
    }
}

// ---------------------------------------------------------------------------
// gemm_k256: deep-pipelined MFMA GEMM for the big (keys) GEMM.
// BM=128, BN=256, BK=64, 512 threads (8 waves, 2Mx4N), 3-deep LDS ring
// (144 KB), counted vmcnt(6) once per K-tile placed BEFORE the end barrier,
// setprio around MFMA cluster, XOR-swizzle chunk^=row&7 (both-sides),
// XCD-bijective block swizzle.
// ---------------------------------------------------------------------------
__global__ __launch_bounds__(512, 1) void gemm_k256(const u16* __restrict__ A,
                                                    const u16* __restrict__ BT,
                                                    const u16* __restrict__ bias,
                                                    u16* __restrict__ Cout,
                                                    int M, int N, int K) {
    __shared__ __align__(16) u16 As[3][128 * 64];   // 48 KB
    __shared__ __align__(16) u16 Bs[3][256 * 64];   // 96 KB
    const int tid = threadIdx.x;
    const int lane = tid & 63;
    const int w = tid >> 6;
    const int bid = blockIdx.x;
    const int swz = (bid & 7) * 32 + (bid >> 3);    // bijective, 256 % 8 == 0
    const int m0 = (swz >> 4) * 128;
    const int n0 = (swz & 15) * 256;
    const int wm = (w >> 2) * 64;
    const int wn = (w & 3) * 64;
    const int q = lane >> 4, r = lane & 15;

    int ra[2], ca[2];
    #pragma unroll
    for (int i = 0; i < 2; i++) {
        int s = i * 512 + tid;
        ra[i] = s >> 3;
        ca[i] = ((s & 7) ^ (ra[i] & 7)) * 8;
    }
    int rb[4], cb[4];
    #pragma unroll
    for (int i = 0; i < 4; i++) {
        int s = i * 512 + tid;
        rb[i] = s >> 3;
        cb[i] = ((s & 7) ^ (rb[i] & 7)) * 8;
    }

    const int nkt = K >> 6;   // 16
    f32x4 acc[4][4] = {};

    #pragma unroll
    for (int tkt = 0; tkt < 2; tkt++) {
        const int kb = tkt * 64;
        #pragma unroll
        for (int i = 0; i < 2; i++)
            gload_lds16(&A[(size_t)(m0 + ra[i]) * K + kb + ca[i]], &As[tkt][(i * 512 + tid) * 8]);
        #pragma unroll
        for (int i = 0; i < 4; i++)
            gload_lds16(&BT[(size_t)(n0 + rb[i]) * K + kb + cb[i]], &Bs[tkt][(i * 512 + tid) * 8]);
    }
    asm volatile("s_waitcnt vmcnt(6)" ::: "memory");   // tile 0 landed
    __builtin_amdgcn_s_barrier();

    for (int kt = 0; kt < nkt; kt++) {
        const int sl = kt % 3;
        const u16* Ab = As[sl];
        const u16* Bb = Bs[sl];
        s16x8 af[4][2], bf[4][2];
        #pragma unroll
        for (int mt = 0; mt < 4; mt++) {
            const int row = wm + mt * 16 + r;
            #pragma unroll
            for (int kh = 0; kh < 2; kh++)
                af[mt][kh] = *(const s16x8*)&Ab[row * 64 + (((kh * 4 + q) ^ (r & 7)) * 8)];
        }
        #pragma unroll
        for (int nt = 0; nt < 4; nt++) {
            const int row = wn + nt * 16 + r;
            #pragma unroll
            for (int kh = 0; kh < 2; kh++)
                bf[nt][kh] = *(const s16x8*)&Bb[row * 64 + (((kh * 4 + q) ^ (r & 7)) * 8)];
        }
        if (kt + 2 < nkt) {
            const int s2 = (kt + 2) % 3;
            const int kb = (kt + 2) * 64;
            #pragma unroll
            for (int i = 0; i < 2; i++)
                gload_lds16(&A[(size_t)(m0 + ra[i]) * K + kb + ca[i]], &As[s2][(i * 512 + tid) * 8]);
            #pragma unroll
            for (int i = 0; i < 4; i++)
                gload_lds16(&BT[(size_t)(n0 + rb[i]) * K + kb + cb[i]], &Bs[s2][(i * 512 + tid) * 8]);
        }
        __builtin_amdgcn_s_barrier();
        __builtin_amdgcn_s_setprio(1);
        #pragma unroll
        for (int kh = 0; kh < 2; kh++)
            #pragma unroll
            for (int mt = 0; mt < 4; mt++)
                #pragma unroll
                for (int nt = 0; nt < 4; nt++)
                    acc[mt][nt] = __builtin_amdgcn_mfma_f32_16x16x32_bf16(
                        af[mt][kh], bf[nt][kh], acc[mt][nt], 0, 0, 0);
        __builtin_amdgcn_s_setprio(0);
        if (kt + 2 < nkt) asm volatile("s_waitcnt vmcnt(6)" ::: "memory");
        else              asm volatile("s_waitcnt vmcnt(0)" ::: "memory");
        __builtin_amdgcn_s_barrier();
    }

    const int cn = lane & 15;
    #pragma unroll
    for (int mt = 0; mt < 4; mt++) {
        #pragma unroll
        for (int i = 0; i < 4; i++) {
            const int gm = m0 + wm + mt * 16 + q * 4 + i;
            const float bv = b2f(bias[gm]);
            #pragma unroll
            for (int nt = 0; nt < 4; nt++) {
                const int gn = n0 + wn + nt * 16 + cn;
                Cout[(size_t)gm * N + gn] = f2b(acc[mt][nt][i] + bv);
            }
        }
    }
}

// ---------------------------------------------------------------------------
// MFMA GEMM (m97 structure) for the small GEMMs. BM=64, BN=128, BK=32,
// 256 threads, gload_lds linear LDS. OB=0: fp32 out.
// ---------------------------------------------------------------------------
template <int BM, int OB>
__global__ __launch_bounds__(256) void gemm_bt(const u16* __restrict__ A,
                                               const u16* __restrict__ BT,
                                               const u16* __restrict__ bias,
                                               void* __restrict__ Cout,
                                               int M, int N, int K) {
    constexpr int MT = BM / 32;
    __shared__ __align__(16) u16 As[BM * 32];
    __shared__ __align__(16) u16 Bs[128 * 32];
    const int tid = threadIdx.x;
    const int lane = tid & 63;
    const int w = tid >> 6;
    const int m0 = blockIdx.y * BM;
    const int n0 = blockIdx.x * 128;
    const int wm = (w >> 1) * (BM / 2);
    const int wn = (w & 1) * 64;

    f32x4 acc[MT][4] = {};

    const int q = lane >> 4, r = lane & 15;

    for (int k0 = 0; k0 < K; k0 += 32) {
        __syncthreads();
        #pragma unroll
        for (int i = 0; i < BM / 64; i++) {
            int s = i * 256 + tid;
            gload_lds16(&A[(size_t)(m0 + (s >> 2)) * K + k0 + (s & 3) * 8], &As[s * 8]);
        }
        #pragma unroll
        for (int i = 0; i < 2; i++) {
            int s = i * 256 + tid;
            gload_lds16(&BT[(size_t)(n0 + (s >> 2)) * K + k0 + (s & 3) * 8], &Bs[s * 8]);
        }
        __syncthreads();

        s16x8 af[MT], bfr[4];
        #pragma unroll
        for (int mt = 0; mt < MT; mt++)
            af[mt] = *(const s16x8*)&As[(wm + mt * 16 + r) * 32 + q * 8];
        #pragma unroll
        for (int nt = 0; nt < 4; nt++)
            bfr[nt] = *(const s16x8*)&Bs[(wn + nt * 16 + r) * 32 + q * 8];
        #pragma unroll
        for (int mt = 0; mt < MT; mt++)
            #pragma unroll
            for (int nt = 0; nt < 4; nt++)
                acc[mt][nt] = __builtin_amdgcn_mfma_f32_16x16x32_bf16(
                    af[mt], bfr[nt], acc[mt][nt], 0, 0, 0);
    }

    const int cn = lane & 15;
    #pragma unroll
    for (int mt = 0; mt < MT; mt++) {
        #pragma unroll
        for (int i = 0; i < 4; i++) {
            int gm = m0 + wm + mt * 16 + q * 4 + i;
            float bv = b2f(bias[gm]);
            #pragma unroll
            for (int nt = 0; nt < 4; nt++) {
                int gn = n0 + wn + nt * 16 + cn;
                float v = acc[mt][nt][i] + bv;
                if (OB)
                    ((u16*)Cout)[(size_t)gm * N + gn] = f2b(v);
                else
                    ((float*)Cout)[(size_t)gm * N + gn] = v;
            }
        }
    }
}

// ---------------------------------------------------------------------------
// score_softmax: fused score reduction + softmax over heads. Grid 64 blocks
// x 512 threads; block owns 64 n-columns, 8 l-chunks of 64.
// ---------------------------------------------------------------------------
__global__ __launch_bounds__(512) void score_softmax(const u16* __restrict__ keys,
                                                     const float* __restrict__ lq,
                                                     float* __restrict__ wm_ws,
                                                     float* __restrict__ out) {
    __shared__ float red[4][8][64];
    const int nl = threadIdx.x & 63;
    const int ls = threadIdx.x >> 6;
    const int n = blockIdx.x * 64 + nl;
    float acc[4] = {0.f, 0.f, 0.f, 0.f};
    #pragma unroll 8
    for (int i = 0; i < 64; i++) {
        const int l = ls * 64 + i;
        const float qv = lq[l * 4096 + n];
        #pragma unroll
        for (int h = 0; h < 4; h++)
            acc[h] += b2f(keys[(size_t)(h * 512 + l) * 4096 + n]) * qv;
    }
    #pragma unroll
    for (int h = 0; h < 4; h++) red[h][ls][nl] = acc[h];
    __syncthreads();
    if (threadIdx.x < 64) {
        const float scale = 0.044194173824159216f;  // 1/sqrt(512)
        float s[4];
        #pragma unroll
        for (int h = 0; h < 4; h++) {
            float v = 0.f;
            #pragma unroll
            for (int c = 0; c < 8; c++) v += red[h][c][nl];
            s[h] = v * scale;
        }
        float mx = fmaxf(fmaxf(s[0], s[1]), fmaxf(s[2], s[3]));
        float e[4], sum = 0.f;
        #pragma unroll
        for (int h = 0; h < 4; h++) { e[h] = expf(s[h] - mx); sum += e[h]; }
        const float inv = 1.0f / sum;
        #pragma unroll
        for (int h = 0; h < 4; h++) {
            float wv = e[h] * inv;
            wm_ws[h * 4096 + n] = wv;
            out[2097152 + (size_t)h * 4096 + n] = wv;
        }
    }
}

// ---------------------------------------------------------------------------
// Fused t + LayerNorm: one block per channel l (512 blocks, all CUs busy).
// ---------------------------------------------------------------------------
__global__ __launch_bounds__(256) void compute_t_ln(const u16* __restrict__ keys,
                                                    const float* __restrict__ lq,
                                                    const float* __restrict__ wm_ws,
                                                    const float* __restrict__ lnw,
                                                    const float* __restrict__ lnb,
                                                    u16* __restrict__ tnorm) {
    const int l = blockIdx.x;
    const int t = threadIdx.x;
    float tv[16];
    float s = 0.f, ss = 0.f;
    #pragma unroll
    for (int j = 0; j < 16; j++) {
        const int n = j * 256 + t;
        float v = lq[l * 4096 + n];
        #pragma unroll
        for (int h = 0; h < 4; h++)
            v += wm_ws[h * 4096 + n] * b2f(keys[(size_t)(h * 512 + l) * 4096 + n]);
        tv[j] = v;
        s += v;
        ss += v * v;
    }
    for (int off = 32; off > 0; off >>= 1) {
        s += __shfl_down(s, off);
        ss += __shfl_down(ss, off);
    }
    __shared__ float bs[4], bss[4];
    const int w = t >> 6, lane = t & 63;
    if (lane == 0) { bs[w] = s; bss[w] = ss; }
    __syncthreads();
    const float S = bs[0] + bs[1] + bs[2] + bs[3];
    const float SS = bss[0] + bss[1] + bss[2] + bss[3];
    const float mu = S * (1.0f / 4096.0f);
    const float rstd = rsqrtf(SS * (1.0f / 4096.0f) - mu * mu + 1e-5f);
    #pragma unroll
    for (int j = 0; j < 16; j++) {
        const int n = j * 256 + t;
        const float v = (tv[j] - mu) * rstd * lnw[n] + lnb[n];
        tnorm[(size_t)l * 4096 + n] = f2b(v);
    }
}

// ---------------------------------------------------------------------------
extern "C" void kernel_launch(void* const* d_in, const int* in_sizes, int n_in,
                              void* d_out, int out_size, void* d_ws, size_t ws_size,
                              hipStream_t stream) {
    const float* pf  = (const float*)d_in[0];
    const float* kp  = (const float*)d_in[1];
    const float* bev = (const float*)d_in[2];
    const float* clw = (const float*)d_in[3];
    const float* clb = (const float*)d_in[4];
    const float* ihw = (const float*)d_in[5];
    const float* ihb = (const float*)d_in[6];
    const float* lnw = (const float*)d_in[7];
    const float* lnb = (const float*)d_in[8];
    const float* cfw = (const float*)d_in[9];
    const float* cfb = (const float*)d_in[10];
    float* out = (float*)d_out;

    char* ws = (char*)d_ws;
    u16*    img     = (u16*)(ws + 0);                    // 8 MB (1024,4096) sorted
    u16*    tnorm   = (u16*)(ws + 0);                    // 4 MB, reuse after T-img
    u16*    imgT    = (u16*)(ws + (8ull << 20));         // 8 MB (4096,1024)
    float*  lq      = (float*)(ws + (8ull << 20));       // 8 MB, reuse after gemm-keys
    u16*    keys    = (u16*)(ws + (16ull << 20));        // 16 MB (2048,4096)
    u16*    pfT     = (u16*)(ws + (32ull << 20));        // 4 MB (4096,512)
    u16*    tT      = (u16*)(ws + (32ull << 20));        // reuse after gemm-lq
    float*  wm_ws   = (float*)(ws + (36ull << 20));
    u16*    canon   = (u16*)  (ws + (36ull << 20) + 131072);
    int4*   pts_off = (int4*) (ws + (42ull << 20));           // 64 KB
    float4* pts_w   = (float4*)(ws + (42ull << 20) + 65536);  // 64 KB
    int*    perm    = (int*)  (ws + (42ull << 20) + 131072);  // 16 KB

    u16* clw_c = canon;
    u16* ihw_c = canon + 262144;
    u16* cfw_c = canon + 2359296;
    u16* clb_c = canon + 2621440;
    u16* ihb_c = canon + 2621952;
    u16* cfb_c = canon + 2632192;

    prep_convert<<<1025, 256, 0, stream>>>(kp, pts_off, pts_w, perm,
                                           clw, ihw, cfw, clb, ihb, lnw, lnb, cfb, canon);
    interp_sorted<<<dim3(1024, 4), 256, 0, stream>>>(bev, pts_off, pts_w, img);
    transpose_both<<<dim3(64, 24), 256, 0, stream>>>(img, pf, imgT, pfT, perm);
    gemm_k256<<<256, 512, 0, stream>>>(ihw_c, imgT, ihb_c, keys, 2048, 4096, 1024);
    gemm_bt<64, 0><<<dim3(32, 8), 256, 0, stream>>>(clw_c, pfT, clb_c, lq, 512, 4096, 512);
    score_softmax<<<64, 512, 0, stream>>>(keys, lq, wm_ws, out);
    compute_t_ln<<<512, 256, 0, stream>>>(keys, lq, wm_ws, lnw, lnb, tnorm);
    transpose_u16<<<dim3(64, 8), 256, 0, stream>>>(tnorm, tT, 512, 4096);
    gemm_bt<64, 0><<<dim3(32, 8), 256, 0, stream>>>(cfw_c, tT, cfb_c, out, 512, 4096, 512);
}